// Round 1
// baseline (431.597 us; speedup 1.0000x reference)
//
#include <hip/hip_runtime.h>

// Quantum state-vector simulation: 20 qubits, batch 8, fp32.
// qubit q <-> bit p = 19-q of the flat index (axis 1 is MSB).
// RY: new0 = c*a + s*b ; new1 = -s*a + c*b  (a = bit=0 amp, b = bit=1 amp)
// CNOT(control bit pc -> target bit pt): swap pairs differing in pt where bit pc = 1.
// Ring chain per layer (in bit terms): (19->18),(18->17),...,(1->0),(0->19).
//
// Schedule: per layer, Pass B (bits {19..13} resident; tile = bits 12..7 fixed)
// then Pass A (bits {13..0} local; contiguous tile). The wrap op (0->19) of layer
// t runs at the start of Pass B of layer t+1. Commutation checked: all reordered
// gate pairs act on disjoint bit sets.

#define LDS4_SIZE 4096  // 4096 float4 = 64 KB

__device__ __forceinline__ int swz(int f) { return f ^ ((f >> 4) & 7); }

template<int K>
__device__ __forceinline__ void ry_reg(float* v, float c, float s) {
#pragma unroll
  for (int i = 0; i < 64; ++i) {
    if (!(i & (1 << K))) {
      float a = v[i], b = v[i | (1 << K)];
      v[i] = c * a + s * b;
      v[i | (1 << K)] = c * b - s * a;
    }
  }
}

// control = register bit J, target = register bit K
template<int J, int K>
__device__ __forceinline__ void cnot_rr(float* v) {
#pragma unroll
  for (int i = 0; i < 64; ++i) {
    if ((i & (1 << J)) && !(i & (1 << K))) {
      float tmp = v[i]; v[i] = v[i | (1 << K)]; v[i | (1 << K)] = tmp;
    }
  }
}

// control = thread-held bit (cond), target = register bit K
template<int K>
__device__ __forceinline__ void cnot_tr(float* v, int cond) {
#pragma unroll
  for (int i = 0; i < 64; ++i) {
    if (!(i & (1 << K))) {
      float a = v[i], b = v[i | (1 << K)];
      v[i] = cond ? b : a;
      v[i | (1 << K)] = cond ? a : b;
    }
  }
}

__global__ void prep_angles(const float* __restrict__ theta, float2* __restrict__ cs) {
  int i = threadIdx.x;
  if (i < 260) {
    float h = 0.5f * theta[i];
    cs[i] = make_float2(cosf(h), sinf(h));
  }
}

// ---------------- Pass B: bits {19..13} resident; tile = (state s, mid m = bits 12..7)
// R1: reg bits {19,18,17,16,1,0}; thread: b15..13 = t7..5, b6..2 = t4..0
// R2: reg bits {19,15,14,13,1,0}; thread: b18..16 = t7..5, b6..2 = t4..0
__global__ __launch_bounds__(256, 2)
void pass_b(const float* __restrict__ src, float* __restrict__ dst,
            const float2* __restrict__ cs, int layer, int do_g4, int do_chain) {
  __shared__ float4 lds4[LDS4_SIZE];
  const int t = threadIdx.x;
  const int blk = blockIdx.x;
  const int s = blk & 7;
  const int m = blk >> 3;
  const size_t sbase4 = ((size_t)s << 18);
  const float4* src4 = (const float4*)src;
  float4* dst4 = (float4*)dst;
  const float2* csl = cs + layer * 20;
  float v[64];

  // load (R1 layout): g4 = s | b19..13 | m | b6..2
#pragma unroll
  for (int rq = 0; rq < 16; ++rq) {
    size_t g4 = sbase4 | ((size_t)((rq << 3) | (t >> 5)) << 11) | ((size_t)m << 5) | (size_t)(t & 31);
    float4 x = src4[g4];
    v[4*rq+0] = x.x; v[4*rq+1] = x.y; v[4*rq+2] = x.z; v[4*rq+3] = x.w;
  }
  // R1 gates
  if (do_g4) cnot_rr<0, 5>(v);                    // (0->19) wrap of previous layer
  { float2 a = csl[0]; ry_reg<5>(v, a.x, a.y); }  // q0  b19
  { float2 a = csl[1]; ry_reg<4>(v, a.x, a.y); }  // q1  b18
  { float2 a = csl[2]; ry_reg<3>(v, a.x, a.y); }  // q2  b17
  { float2 a = csl[3]; ry_reg<2>(v, a.x, a.y); }  // q3  b16
  if (do_chain) {
    cnot_rr<5, 4>(v);  // (19->18)
    cnot_rr<4, 3>(v);  // (18->17)
    cnot_rr<3, 2>(v);  // (17->16)
  }
  // transpose: write R1 layout
#pragma unroll
  for (int rq = 0; rq < 16; ++rq) {
    int f = (rq << 8) | ((t >> 5) << 5) | (t & 31);
    lds4[swz(f)] = make_float4(v[4*rq], v[4*rq+1], v[4*rq+2], v[4*rq+3]);
  }
  __syncthreads();
  // read R2 layout: rq = (b19, b15, b14, b13)
#pragma unroll
  for (int rq = 0; rq < 16; ++rq) {
    int f = ((rq >> 3) << 11) | (((t >> 5) & 7) << 8) | ((rq & 7) << 5) | (t & 31);
    float4 x = lds4[swz(f)];
    v[4*rq+0] = x.x; v[4*rq+1] = x.y; v[4*rq+2] = x.z; v[4*rq+3] = x.w;
  }
  // R2 gates
  { float2 a = csl[4]; ry_reg<4>(v, a.x, a.y); }  // q4  b15
  { float2 a = csl[5]; ry_reg<3>(v, a.x, a.y); }  // q5  b14
  { float2 a = csl[6]; ry_reg<2>(v, a.x, a.y); }  // q6  b13
  if (do_chain) {
    cnot_tr<4>(v, (t >> 5) & 1);  // (16->15), cond b16 = t5
    cnot_rr<4, 3>(v);             // (15->14)
    cnot_rr<3, 2>(v);             // (14->13)
  }
  // write back R2 layout (same addresses this thread read -> no barrier needed)
#pragma unroll
  for (int rq = 0; rq < 16; ++rq) {
    int f = ((rq >> 3) << 11) | (((t >> 5) & 7) << 8) | ((rq & 7) << 5) | (t & 31);
    lds4[swz(f)] = make_float4(v[4*rq], v[4*rq+1], v[4*rq+2], v[4*rq+3]);
  }
  __syncthreads();
  // read R1 layout, store coalesced
#pragma unroll
  for (int rq = 0; rq < 16; ++rq) {
    int f = (rq << 8) | ((t >> 5) << 5) | (t & 31);
    float4 x = lds4[swz(f)];
    size_t g4 = sbase4 | ((size_t)((rq << 3) | (t >> 5)) << 11) | ((size_t)m << 5) | (size_t)(t & 31);
    dst4[g4] = x;
  }
}

// ---------------- Pass A: bits {13..0} local; contiguous tile (state s, hi m = bits 19..14)
// R1: reg {12,11,10,9,1,0};  thread: b13 = t7, b8..2 = t6..0
// R2: reg {8,7,6,5,1,0};     thread: b13 = t7, b12..9 = t6..3, b4..2 = t2..0
// R3: reg {5,4,3,2,1,0};     thread: b13..6 = t7..0
__global__ __launch_bounds__(256, 2)
void pass_a(const float* __restrict__ src, float* __restrict__ dst,
            const float2* __restrict__ cs, int layer, int do_chain, int do_meas,
            float* __restrict__ outp) {
  __shared__ float4 lds4[LDS4_SIZE];
  const int t = threadIdx.x;
  const int blk = blockIdx.x;
  const int s = blk & 7;
  const int m = blk >> 3;
  const size_t base4 = ((size_t)s << 18) | ((size_t)m << 12);
  const float4* src4 = (const float4*)src;
  float4* dst4 = (float4*)dst;
  const float2* csl = cs + layer * 20;
  float v[64];

  // load (R1 layout): f = b13..2 = (t7, rq, t6..0)
#pragma unroll
  for (int rq = 0; rq < 16; ++rq) {
    int f = ((t >> 7) << 11) | (rq << 7) | (t & 127);
    float4 x = src4[base4 + f];
    v[4*rq+0] = x.x; v[4*rq+1] = x.y; v[4*rq+2] = x.z; v[4*rq+3] = x.w;
  }
  // R1 gates
  { float2 a = csl[7];  ry_reg<5>(v, a.x, a.y); }  // q7  b12
  { float2 a = csl[8];  ry_reg<4>(v, a.x, a.y); }  // q8  b11
  { float2 a = csl[9];  ry_reg<3>(v, a.x, a.y); }  // q9  b10
  { float2 a = csl[10]; ry_reg<2>(v, a.x, a.y); }  // q10 b9
  if (do_chain) {
    cnot_tr<5>(v, (t >> 7) & 1);  // (13->12), cond b13 = t7
    cnot_rr<5, 4>(v);             // (12->11)
    cnot_rr<4, 3>(v);             // (11->10)
    cnot_rr<3, 2>(v);             // (10->9)
  }
  // T1 write (R1 layout)
#pragma unroll
  for (int rq = 0; rq < 16; ++rq) {
    int f = ((t >> 7) << 11) | (rq << 7) | (t & 127);
    lds4[swz(f)] = make_float4(v[4*rq], v[4*rq+1], v[4*rq+2], v[4*rq+3]);
  }
  __syncthreads();
  // R2 read
#pragma unroll
  for (int rq = 0; rq < 16; ++rq) {
    int f = ((t >> 7) << 11) | (((t >> 3) & 15) << 7) | (rq << 3) | (t & 7);
    float4 x = lds4[swz(f)];
    v[4*rq+0] = x.x; v[4*rq+1] = x.y; v[4*rq+2] = x.z; v[4*rq+3] = x.w;
  }
  // R2 gates
  { float2 a = csl[11]; ry_reg<5>(v, a.x, a.y); }  // q11 b8
  { float2 a = csl[12]; ry_reg<4>(v, a.x, a.y); }  // q12 b7
  { float2 a = csl[13]; ry_reg<3>(v, a.x, a.y); }  // q13 b6
  { float2 a = csl[14]; ry_reg<2>(v, a.x, a.y); }  // q14 b5
  if (do_chain) {
    cnot_tr<5>(v, (t >> 3) & 1);  // (9->8), cond b9 = t3
    cnot_rr<5, 4>(v);             // (8->7)
    cnot_rr<4, 3>(v);             // (7->6)
    cnot_rr<3, 2>(v);             // (6->5)
  }
  // T2 write (same addresses this thread read in R2 -> no barrier needed before)
#pragma unroll
  for (int rq = 0; rq < 16; ++rq) {
    int f = ((t >> 7) << 11) | (((t >> 3) & 15) << 7) | (rq << 3) | (t & 7);
    lds4[swz(f)] = make_float4(v[4*rq], v[4*rq+1], v[4*rq+2], v[4*rq+3]);
  }
  __syncthreads();
  // R3 read: f = (t<<4) | rq   (reg bits = b5..0)
#pragma unroll
  for (int rq = 0; rq < 16; ++rq) {
    int f = (t << 4) | rq;
    float4 x = lds4[swz(f)];
    v[4*rq+0] = x.x; v[4*rq+1] = x.y; v[4*rq+2] = x.z; v[4*rq+3] = x.w;
  }
  // R3 gates
  { float2 a = csl[15]; ry_reg<4>(v, a.x, a.y); }  // q15 b4
  { float2 a = csl[16]; ry_reg<3>(v, a.x, a.y); }  // q16 b3
  { float2 a = csl[17]; ry_reg<2>(v, a.x, a.y); }  // q17 b2
  { float2 a = csl[18]; ry_reg<1>(v, a.x, a.y); }  // q18 b1
  { float2 a = csl[19]; ry_reg<0>(v, a.x, a.y); }  // q19 b0
  if (do_chain) {
    cnot_rr<5, 4>(v);  // (5->4)
    cnot_rr<4, 3>(v);  // (4->3)
    cnot_rr<3, 2>(v);  // (3->2)
    cnot_rr<2, 1>(v);  // (2->1)
    cnot_rr<1, 0>(v);  // (1->0)
  }

  if (!do_meas) {
    // T3 write (same addresses as R3 read) then coalesced store via R1 layout
#pragma unroll
    for (int rq = 0; rq < 16; ++rq) {
      int f = (t << 4) | rq;
      lds4[swz(f)] = make_float4(v[4*rq], v[4*rq+1], v[4*rq+2], v[4*rq+3]);
    }
    __syncthreads();
#pragma unroll
    for (int rq = 0; rq < 16; ++rq) {
      int f = ((t >> 7) << 11) | (rq << 7) | (t & 127);
      float4 x = lds4[swz(f)];
      dst4[base4 + f] = x;
    }
  } else {
    // measurement: bins by b2..0 = r & 7
    float p[8];
#pragma unroll
    for (int b = 0; b < 8; ++b) p[b] = 0.f;
#pragma unroll
    for (int r = 0; r < 64; ++r) p[r & 7] += v[r] * v[r];
#pragma unroll
    for (int b = 0; b < 8; ++b) {
      p[b] += __shfl_xor(p[b], 32);
      p[b] += __shfl_xor(p[b], 16);
      p[b] += __shfl_xor(p[b], 8);
      p[b] += __shfl_xor(p[b], 4);
      p[b] += __shfl_xor(p[b], 2);
      p[b] += __shfl_xor(p[b], 1);
    }
    __syncthreads();
    float* red = (float*)lds4;
    if ((t & 63) == 0) {
#pragma unroll
      for (int b = 0; b < 8; ++b) red[(t >> 6) * 8 + b] = p[b];
    }
    __syncthreads();
    if (t < 8) {
      float sum = red[t] + red[8 + t] + red[16 + t] + red[24 + t];
      atomicAdd(outp + s * 8 + t, sum);
    }
  }
}

extern "C" void kernel_launch(void* const* d_in, const int* in_sizes, int n_in,
                              void* d_out, int out_size, void* d_ws, size_t ws_size,
                              hipStream_t stream) {
  const float* x = (const float*)d_in[0];
  const float* theta = (const float*)d_in[1];
  float* outp = (float*)d_out;
  float2* cs = (float2*)d_ws;

  const size_t STATE_BYTES = (size_t)8 << 22;  // 8 states * 2^20 * 4B = 32 MB
  bool ws_state = ws_size >= STATE_BYTES + 8192;
  float* state = ws_state ? (float*)((char*)d_ws + 8192) : (float*)d_in[0];

  hipMemsetAsync(d_out, 0, 64 * sizeof(float), stream);
  prep_angles<<<1, 512, 0, stream>>>(theta, cs);

  for (int L = 0; L < 13; ++L) {
    const float* srcB = (L == 0) ? x : state;
    pass_b<<<512, 256, 0, stream>>>(srcB, state, cs, L, (L >= 1) ? 1 : 0, (L < 12) ? 1 : 0);
    pass_a<<<512, 256, 0, stream>>>(state, state, cs, L, (L < 12) ? 1 : 0, (L == 12) ? 1 : 0, outp);
  }
}

// Round 2
// 411.037 us; speedup vs baseline: 1.0500x; 1.0500x over previous
//
#include <hip/hip_runtime.h>

// 20-qubit state-vector sim, batch 8, fp32. qubit q <-> bit (19-q), axis 1 MSB.
// RY: new0 = c*a + s*b ; new1 = c*b - s*a. Chain per layer: (19->18)...(1->0),(0->19).
// High pass: resident {19..11}u{3..0}, tile m = b10..b4. RY b19..b11, chain 19->18..12->11,
//            deferred wrap (0->19) of previous layer at entry.
// Low pass:  resident {12..0}, tile m = b19..b13. RY b10..b0, chain 11->10..1->0.
// 1024 blocks (8 states x 128 tiles), 256 thr, v[32] = 2^13 amps/block, 32 KB LDS
// -> 4 blocks/CU, 16 waves/CU. XCD pinning: state s = blk & 7.

#define LDSN 2048  // float4 entries = 32 KB

__device__ __forceinline__ int swzH(int l) { return l ^ (((l >> 5) & 1) << 2); }
__device__ __forceinline__ int swzL(int l) { return l ^ ((l >> 3) & 7); }

template<int K>
__device__ __forceinline__ void ry32(float* v, float c, float s) {
#pragma unroll
  for (int i = 0; i < 32; ++i)
    if (!(i & (1 << K))) {
      float a = v[i], b = v[i | (1 << K)];
      v[i] = c * a + s * b;
      v[i | (1 << K)] = c * b - s * a;
    }
}
template<int J, int K>
__device__ __forceinline__ void cnot_rr32(float* v) {
#pragma unroll
  for (int i = 0; i < 32; ++i)
    if ((i & (1 << J)) && !(i & (1 << K))) {
      float tmp = v[i]; v[i] = v[i | (1 << K)]; v[i | (1 << K)] = tmp;
    }
}
template<int K>
__device__ __forceinline__ void cnot_tr32(float* v, int cond) {
#pragma unroll
  for (int i = 0; i < 32; ++i)
    if (!(i & (1 << K))) {
      float a = v[i], b = v[i | (1 << K)];
      v[i] = cond ? b : a;
      v[i | (1 << K)] = cond ? a : b;
    }
}

__global__ void prep_angles(const float* __restrict__ theta, float2* __restrict__ cs) {
  int i = threadIdx.x;
  if (i < 260) {
    float h = 0.5f * theta[i];
    cs[i] = make_float2(cosf(h), sinf(h));
  }
}

// ---------------- High pass ----------------
// R1: reg {19,18,17,1,0}; thread t7..t2 = b16..b11, t1t0 = b3b2
// R2: reg {16,15,14,1,0}; thread t7..t5 = b19..b17, t4..t2 = b13..b11, t1t0 = b3b2
// R3: reg {13,12,11,1,0}; thread t7..t2 = b19..b14, t1t0 = b3b2
__global__ __launch_bounds__(256, 4)
void pass_hi(const float* __restrict__ src, float* __restrict__ dst,
             const float2* __restrict__ cs, int layer, int do_wrap, int do_chain) {
  __shared__ float4 lds4[LDSN];
  const int t = threadIdx.x;
  const int blk = blockIdx.x;
  const int s = blk & 7;
  const int m = blk >> 3;  // b10..b4
  const size_t sbase = ((size_t)s << 18) | ((size_t)m << 2);
  const float4* src4 = (const float4*)src;
  float4* dst4 = (float4*)dst;
  const float2* csl = cs + layer * 20;
  float v[32];

  // R1 load
#pragma unroll
  for (int rq = 0; rq < 8; ++rq) {
    size_t g4 = sbase | ((size_t)rq << 15) | ((size_t)(t >> 2) << 9) | (size_t)(t & 3);
    float4 x = src4[g4];
    v[4*rq] = x.x; v[4*rq+1] = x.y; v[4*rq+2] = x.z; v[4*rq+3] = x.w;
  }
  if (do_wrap) cnot_rr32<0, 4>(v);                 // wrap (0->19) of previous layer
  { float2 a = csl[0]; ry32<4>(v, a.x, a.y); }     // q0  b19
  { float2 a = csl[1]; ry32<3>(v, a.x, a.y); }     // q1  b18
  { float2 a = csl[2]; ry32<2>(v, a.x, a.y); }     // q2  b17
  if (do_chain) { cnot_rr32<4, 3>(v); cnot_rr32<3, 2>(v); }  // (19->18),(18->17)
  // T1 write (R1 layout): l = (rq<<8) | t
#pragma unroll
  for (int rq = 0; rq < 8; ++rq)
    lds4[swzH((rq << 8) | t)] = make_float4(v[4*rq], v[4*rq+1], v[4*rq+2], v[4*rq+3]);
  __syncthreads();
  // R2 read
#pragma unroll
  for (int rq = 0; rq < 8; ++rq) {
    int l = ((t >> 5) << 8) | (rq << 5) | (((t >> 2) & 7) << 2) | (t & 3);
    float4 x = lds4[swzH(l)];
    v[4*rq] = x.x; v[4*rq+1] = x.y; v[4*rq+2] = x.z; v[4*rq+3] = x.w;
  }
  { float2 a = csl[3]; ry32<4>(v, a.x, a.y); }     // q3  b16
  { float2 a = csl[4]; ry32<3>(v, a.x, a.y); }     // q4  b15
  { float2 a = csl[5]; ry32<2>(v, a.x, a.y); }     // q5  b14
  if (do_chain) {
    cnot_tr32<4>(v, (t >> 5) & 1);                 // (17->16), ctrl b17 = t5
    cnot_rr32<4, 3>(v);                            // (16->15)
    cnot_rr32<3, 2>(v);                            // (15->14)
  }
  // T2 write back (same addresses as R2 read; per-thread sets are disjoint)
#pragma unroll
  for (int rq = 0; rq < 8; ++rq) {
    int l = ((t >> 5) << 8) | (rq << 5) | (((t >> 2) & 7) << 2) | (t & 3);
    lds4[swzH(l)] = make_float4(v[4*rq], v[4*rq+1], v[4*rq+2], v[4*rq+3]);
  }
  __syncthreads();
  // R3 read
#pragma unroll
  for (int rq = 0; rq < 8; ++rq) {
    int l = ((t >> 2) << 5) | (rq << 2) | (t & 3);
    float4 x = lds4[swzH(l)];
    v[4*rq] = x.x; v[4*rq+1] = x.y; v[4*rq+2] = x.z; v[4*rq+3] = x.w;
  }
  { float2 a = csl[6]; ry32<4>(v, a.x, a.y); }     // q6  b13
  { float2 a = csl[7]; ry32<3>(v, a.x, a.y); }     // q7  b12
  { float2 a = csl[8]; ry32<2>(v, a.x, a.y); }     // q8  b11
  if (do_chain) {
    cnot_tr32<4>(v, (t >> 2) & 1);                 // (14->13), ctrl b14 = t2
    cnot_rr32<4, 3>(v);                            // (13->12)
    cnot_rr32<3, 2>(v);                            // (12->11)
  }
  // store (R3 layout)
#pragma unroll
  for (int rq = 0; rq < 8; ++rq) {
    size_t g4 = sbase | ((size_t)(t >> 2) << 12) | ((size_t)rq << 9) | (size_t)(t & 3);
    dst4[g4] = make_float4(v[4*rq], v[4*rq+1], v[4*rq+2], v[4*rq+3]);
  }
}

// ---------------- Low pass ----------------
// R1: reg {10,9,8,1,0};  thread t7t6 = b12b11, t5..t0 = b7..b2
// R2: reg {7,6,5,1,0};   thread t7..t3 = b12..b8, t2..t0 = b4..b2
// R3: reg {4,3,2,1,0};   thread t7..t0 = b12..b5
__global__ __launch_bounds__(256, 4)
void pass_lo(const float* __restrict__ src, float* __restrict__ dst,
             const float2* __restrict__ cs, int layer, int do_chain, int do_meas,
             float* __restrict__ outp) {
  __shared__ float4 lds4[LDSN];
  const int t = threadIdx.x;
  const int blk = blockIdx.x;
  const int s = blk & 7;
  const int m = blk >> 3;  // b19..b13
  const size_t base4 = ((size_t)s << 18) | ((size_t)m << 11);
  const float4* src4 = (const float4*)src;
  float4* dst4 = (float4*)dst;
  const float2* csl = cs + layer * 20;
  float v[32];

  // R1 load (contiguous, fully coalesced)
#pragma unroll
  for (int rq = 0; rq < 8; ++rq) {
    int l = ((t >> 6) << 9) | (rq << 6) | (t & 63);
    float4 x = src4[base4 + l];
    v[4*rq] = x.x; v[4*rq+1] = x.y; v[4*rq+2] = x.z; v[4*rq+3] = x.w;
  }
  { float2 a = csl[9];  ry32<4>(v, a.x, a.y); }    // q9  b10
  { float2 a = csl[10]; ry32<3>(v, a.x, a.y); }    // q10 b9
  { float2 a = csl[11]; ry32<2>(v, a.x, a.y); }    // q11 b8
  if (do_chain) {
    cnot_tr32<4>(v, (t >> 6) & 1);                 // (11->10), ctrl b11 = t6
    cnot_rr32<4, 3>(v);                            // (10->9)
    cnot_rr32<3, 2>(v);                            // (9->8)
  }
  // T1 write (R1 layout)
#pragma unroll
  for (int rq = 0; rq < 8; ++rq) {
    int l = ((t >> 6) << 9) | (rq << 6) | (t & 63);
    lds4[swzL(l)] = make_float4(v[4*rq], v[4*rq+1], v[4*rq+2], v[4*rq+3]);
  }
  __syncthreads();
  // R2 read
#pragma unroll
  for (int rq = 0; rq < 8; ++rq) {
    int l = ((t >> 3) << 6) | (rq << 3) | (t & 7);
    float4 x = lds4[swzL(l)];
    v[4*rq] = x.x; v[4*rq+1] = x.y; v[4*rq+2] = x.z; v[4*rq+3] = x.w;
  }
  { float2 a = csl[12]; ry32<4>(v, a.x, a.y); }    // q12 b7
  { float2 a = csl[13]; ry32<3>(v, a.x, a.y); }    // q13 b6
  { float2 a = csl[14]; ry32<2>(v, a.x, a.y); }    // q14 b5
  if (do_chain) {
    cnot_tr32<4>(v, (t >> 3) & 1);                 // (8->7), ctrl b8 = t3
    cnot_rr32<4, 3>(v);                            // (7->6)
    cnot_rr32<3, 2>(v);                            // (6->5)
  }
  // T2 write back (same addresses)
#pragma unroll
  for (int rq = 0; rq < 8; ++rq) {
    int l = ((t >> 3) << 6) | (rq << 3) | (t & 7);
    lds4[swzL(l)] = make_float4(v[4*rq], v[4*rq+1], v[4*rq+2], v[4*rq+3]);
  }
  __syncthreads();
  // R3 read
#pragma unroll
  for (int rq = 0; rq < 8; ++rq) {
    int l = (t << 3) | rq;
    float4 x = lds4[swzL(l)];
    v[4*rq] = x.x; v[4*rq+1] = x.y; v[4*rq+2] = x.z; v[4*rq+3] = x.w;
  }
  { float2 a = csl[15]; ry32<4>(v, a.x, a.y); }    // q15 b4
  { float2 a = csl[16]; ry32<3>(v, a.x, a.y); }    // q16 b3
  { float2 a = csl[17]; ry32<2>(v, a.x, a.y); }    // q17 b2
  { float2 a = csl[18]; ry32<1>(v, a.x, a.y); }    // q18 b1
  { float2 a = csl[19]; ry32<0>(v, a.x, a.y); }    // q19 b0
  if (do_chain) {
    cnot_tr32<4>(v, t & 1);                        // (5->4), ctrl b5 = t0
    cnot_rr32<4, 3>(v);                            // (4->3)
    cnot_rr32<3, 2>(v);                            // (3->2)
    cnot_rr32<2, 1>(v);                            // (2->1)
    cnot_rr32<1, 0>(v);                            // (1->0)
  }

  if (!do_meas) {
    // T3 write (R3 layout), then coalesced store via R1 layout
#pragma unroll
    for (int rq = 0; rq < 8; ++rq) {
      int l = (t << 3) | rq;
      lds4[swzL(l)] = make_float4(v[4*rq], v[4*rq+1], v[4*rq+2], v[4*rq+3]);
    }
    __syncthreads();
#pragma unroll
    for (int rq = 0; rq < 8; ++rq) {
      int l = ((t >> 6) << 9) | (rq << 6) | (t & 63);
      float4 x = lds4[swzL(l)];
      dst4[base4 + l] = x;
    }
  } else {
    // measurement: bin = (b2,b1,b0); in R3, b2 = rq&1, b1b0 = j
    float p[8];
#pragma unroll
    for (int b = 0; b < 8; ++b) p[b] = 0.f;
#pragma unroll
    for (int rq = 0; rq < 8; ++rq)
#pragma unroll
      for (int j = 0; j < 4; ++j) {
        float a = v[4*rq + j];
        p[((rq & 1) << 2) | j] += a * a;
      }
#pragma unroll
    for (int b = 0; b < 8; ++b) {
      p[b] += __shfl_xor(p[b], 32);
      p[b] += __shfl_xor(p[b], 16);
      p[b] += __shfl_xor(p[b], 8);
      p[b] += __shfl_xor(p[b], 4);
      p[b] += __shfl_xor(p[b], 2);
      p[b] += __shfl_xor(p[b], 1);
    }
    __syncthreads();
    float* red = (float*)lds4;
    if ((t & 63) == 0) {
#pragma unroll
      for (int b = 0; b < 8; ++b) red[(t >> 6) * 8 + b] = p[b];
    }
    __syncthreads();
    if (t < 8) {
      float sum = red[t] + red[8 + t] + red[16 + t] + red[24 + t];
      atomicAdd(outp + s * 8 + t, sum);
    }
  }
}

extern "C" void kernel_launch(void* const* d_in, const int* in_sizes, int n_in,
                              void* d_out, int out_size, void* d_ws, size_t ws_size,
                              hipStream_t stream) {
  const float* x = (const float*)d_in[0];
  const float* theta = (const float*)d_in[1];
  float* outp = (float*)d_out;
  float2* cs = (float2*)d_ws;
  float* state = (float*)((char*)d_ws + 8192);

  hipMemsetAsync(d_out, 0, 64 * sizeof(float), stream);
  prep_angles<<<1, 512, 0, stream>>>(theta, cs);

  for (int L = 0; L < 13; ++L) {
    const float* srcH = (L == 0) ? x : state;
    pass_hi<<<1024, 256, 0, stream>>>(srcH, state, cs, L, (L >= 1) ? 1 : 0, (L < 12) ? 1 : 0);
    pass_lo<<<1024, 256, 0, stream>>>(state, state, cs, L, (L < 12) ? 1 : 0, (L == 12) ? 1 : 0, outp);
  }
}